// Round 4
// baseline (26691.943 us; speedup 1.0000x reference)
//
#include <hip/hip_runtime.h>

// BasicLSTM on MI355X (gfx950) — persistent-chunk recurrent kernel.
// Phase-separated layers. Per layer: chunked input GEMM (fp16 MFMA) into Gc,
// then ONE persistent kernel per chunk runs CH timesteps with an in-kernel
// grid barrier (64 blocks). h exchanged via LLC-coherent (volatile sc0/sc1)
// loads/stores => no cache invalidates, Wh stays hot in each XCD's L2.
//
// Workspace layout (bytes):
//   WpH0 @ 0        : 8,388,608   packed Wh layer0 (fp16 B-frag)
//   WpH1 @ 8388608  : 8,388,608   packed Wh layer1
//   WpX  @ 16777216 : 8,388,608   packed Wx (re-packed per layer phase)
//   ring @ 25165824 :   524,288   4 slots x 64x1024 fp16 (2 per layer)
//   cb   @ 25690112 :   524,288   cell state 2 x 64x1024 fp32
//   bar  @ 26214400 :     4,096   grid-barrier counter (+pad)
//   Gc   @ 26218496 : CH*524,288  gate buffer
// tiers CH in {32,16,8,4} -> 43.0 / 34.6 / 30.4 / 28.3 MB

typedef _Float16 half8 __attribute__((ext_vector_type(8)));
typedef float    f32x4 __attribute__((ext_vector_type(4)));

#define SEQ 512
#define BATCH 64
#define HID 1024
#define NBLK 64
#define SL 65536   // BATCH*HID

// ---- fallback: write zeros over all of d_out (guarantees >=1 launch) -------
__global__ void zero_out(float* __restrict__ out) {
    size_t i = (size_t)blockIdx.x * blockDim.x + threadIdx.x;
    ((f32x4*)out)[i] = f32x4{0.f, 0.f, 0.f, 0.f};
}

// ---- zero the barrier counter ----------------------------------------------
__global__ void zero_bar(unsigned* __restrict__ bar) {
    bar[threadIdx.x] = 0u;
}

// ---- pack one 1024x4096 fp32 matrix (row stride 4096) into fp16 B-frag -----
// B-frag 16x16x32: lane L holds B[k = kt*32 + (L>>4)*8 + j][n = nt*16 + (L&15)]
// packed offset = ((nt*32 + kt)*64 + L)*8 + j   (halfs)
__global__ void pack1(const float* __restrict__ src, _Float16* __restrict__ dst) {
    int nt   = blockIdx.x;        // 0..255
    int ktg  = blockIdx.y;        // 0..7
    int lane = threadIdx.x & 63;
    int wave = threadIdx.x >> 6;
    int kt   = ktg * 4 + wave;    // 0..31
    int k0 = kt * 32 + (lane >> 4) * 8;
    int n  = nt * 16 + (lane & 15);
    half8 v;
#pragma unroll
    for (int j = 0; j < 8; ++j)
        v[j] = (_Float16)src[(size_t)(k0 + j) * 4096 + n];
    *(half8*)(dst + ((size_t)(nt * 32 + kt) * 64 + lane) * 8) = v;
}

// ---- c0 -> cb ---------------------------------------------------------------
__global__ void copy_f4(const float* __restrict__ src, float* __restrict__ dst) {
    int i = blockIdx.x * blockDim.x + threadIdx.x;
    ((f32x4*)dst)[i] = ((const f32x4*)src)[i];
}

// ---- chunk input GEMM: G = A(fp32) @ Wpacked + bias -> fp16 ----------------
// A: [MC][1024] fp32 row-major. Tile 128x128, 4 waves (2x2 of 64x64).
__global__ __launch_bounds__(256) void gemm_in(
    const float* __restrict__ A, const _Float16* __restrict__ Bp,
    const float* __restrict__ bias, _Float16* __restrict__ Gout)
{
    int lane = threadIdx.x & 63;
    int wave = threadIdx.x >> 6;
    int wm = wave & 1, wn = wave >> 1;
    int m0 = blockIdx.x * 128 + wm * 64;
    int n0 = blockIdx.y * 128 + wn * 64;
    int col = lane & 15, quad = lane >> 4;
    f32x4 acc[4][4] = {};
    const float*    Arow  = A + (size_t)(m0 + col) * 1024 + quad * 8;
    const _Float16* Bbase = Bp + (size_t)(n0 >> 4) * 16384 + (size_t)lane * 8;
    for (int kt = 0; kt < 32; ++kt) {
        half8 a[4], b[4];
#pragma unroll
        for (int i = 0; i < 4; ++i) {
            const float* p = Arow + (size_t)i * 16 * 1024 + kt * 32;
            f32x4 v0 = *(const f32x4*)(p);
            f32x4 v1 = *(const f32x4*)(p + 4);
            a[i][0] = (_Float16)v0[0]; a[i][1] = (_Float16)v0[1];
            a[i][2] = (_Float16)v0[2]; a[i][3] = (_Float16)v0[3];
            a[i][4] = (_Float16)v1[0]; a[i][5] = (_Float16)v1[1];
            a[i][6] = (_Float16)v1[2]; a[i][7] = (_Float16)v1[3];
        }
#pragma unroll
        for (int j = 0; j < 4; ++j)
            b[j] = *(const half8*)(Bbase + (size_t)j * 16384 + kt * 512);
#pragma unroll
        for (int i = 0; i < 4; ++i)
#pragma unroll
            for (int j = 0; j < 4; ++j)
                acc[i][j] = __builtin_amdgcn_mfma_f32_16x16x32_f16(a[i], b[j], acc[i][j], 0, 0, 0);
    }
#pragma unroll
    for (int j = 0; j < 4; ++j) {
        int n = n0 + j * 16 + col;
        float bv = bias[n];
#pragma unroll
        for (int i = 0; i < 4; ++i)
#pragma unroll
            for (int r = 0; r < 4; ++r) {
                int m = m0 + i * 16 + quad * 4 + r;
                Gout[(size_t)m * 4096 + n] = (_Float16)(acc[i][j][r] + bv);
            }
    }
}

// ---- persistent chunk kernel: nsteps LSTM timesteps, 64 blocks -------------
// Block g owns hidden cols [16g,16g+16) (4 gate strips) for all 64 batch rows.
// Grid barrier per step: relaxed agent atomics on bar; h ring accessed with
// volatile (LLC-coherent) ops so no cache-wide invalidates are needed.
__global__ __launch_bounds__(256, 1) void lstm_chunk(
    const _Float16* __restrict__ Whp, const _Float16* __restrict__ Gc,
    float* __restrict__ cb, _Float16* __restrict__ ring,
    const float* __restrict__ h0init, float* __restrict__ hist32,
    float* __restrict__ lasth, float* __restrict__ lastc,
    unsigned* __restrict__ bar, unsigned bar_base, int t0, int nsteps)
{
    int lane = threadIdx.x & 63;
    int wave = threadIdx.x >> 6;
    int g = blockIdx.x;
    int col = lane & 15, quad = lane >> 4;
    int m0 = wave * 16;
    int hid = g * 16 + col;

    // cell state for this thread: batch rows m0+quad*4+r, col hid
    float creg[4];
#pragma unroll
    for (int r = 0; r < 4; ++r)
        creg[r] = cb[(size_t)(m0 + quad * 4 + r) * HID + hid];

    // packed Wh fragment base: offset(nt,kt) = ((nt*32+kt)*64+lane)*8, nt=gate*64+g
    const _Float16* bbase = Whp + (size_t)g * 16384 + (size_t)lane * 8;

    for (int s = 0; s < nsteps; ++s) {
        int t = t0 + s;
        // ---- A-fragments: h_prev[m0+col][kt*32 + quad*8 + 0..7] ----
        half8 af[32];
        if (h0init != nullptr && s == 0 && t0 == 0) {
            const float* hp = h0init + (size_t)(m0 + col) * HID + quad * 8;
#pragma unroll
            for (int kt = 0; kt < 32; ++kt) {
                f32x4 v0 = *(const f32x4*)(hp + kt * 32);
                f32x4 v1 = *(const f32x4*)(hp + kt * 32 + 4);
                af[kt][0] = (_Float16)v0[0]; af[kt][1] = (_Float16)v0[1];
                af[kt][2] = (_Float16)v0[2]; af[kt][3] = (_Float16)v0[3];
                af[kt][4] = (_Float16)v1[0]; af[kt][5] = (_Float16)v1[1];
                af[kt][6] = (_Float16)v1[2]; af[kt][7] = (_Float16)v1[3];
            }
        } else {
            const _Float16* hp = ring + (size_t)((t - 1) & 1) * SL
                               + (size_t)(m0 + col) * HID + quad * 8;
#pragma unroll
            for (int kt = 0; kt < 32; ++kt)
                af[kt] = *(const volatile half8*)(hp + kt * 32);  // sc0/sc1: LLC-coherent
        }
        // ---- recurrent MFMAs: 4 gate strips ----
        f32x4 acc[4] = {};
#pragma unroll
        for (int kt = 0; kt < 32; ++kt) {
#pragma unroll
            for (int gi = 0; gi < 4; ++gi) {
                half8 b = *(const half8*)(bbase + (size_t)gi * 1048576 + (size_t)kt * 512);
                acc[gi] = __builtin_amdgcn_mfma_f32_16x16x32_f16(af[kt], b, acc[gi], 0, 0, 0);
            }
        }
        // ---- epilogue: add input gates, cell update, write h ----
        _Float16* ringw = ring + (size_t)(t & 1) * SL;
        float* h32w = hist32 + (size_t)t * SL;
#pragma unroll
        for (int r = 0; r < 4; ++r) {
            int b = m0 + quad * 4 + r;
            const _Float16* Gr = Gc + (size_t)s * (4 * SL) + (size_t)b * 4096;
            float gi_ = acc[0][r] + (float)Gr[hid];
            float gj_ = acc[1][r] + (float)Gr[1024 + hid];
            float gf_ = acc[2][r] + (float)Gr[2048 + hid];
            float go_ = acc[3][r] + (float)Gr[3072 + hid];
            float iv = 1.f / (1.f + __expf(-gi_));
            float jv = tanhf(gj_);
            float fv = 1.f / (1.f + __expf(-gf_));
            float ov = 1.f / (1.f + __expf(-go_));
            float cn = creg[r] * fv + iv * jv;
            float hn = tanhf(cn) * ov;
            creg[r] = cn;
            size_t idx = (size_t)b * HID + hid;
            *(volatile _Float16*)(ringw + idx) = (_Float16)hn;  // coherent for next step
            h32w[idx] = hn;                                     // history / final output
            if (lasth != nullptr && s == nsteps - 1) {
                lasth[idx] = hn; lastc[idx] = cn;
            }
        }
        // ---- grid barrier (no cache invalidates) ----
        asm volatile("s_waitcnt vmcnt(0)" ::: "memory");  // per-wave store drain
        __syncthreads();                                   // drains all waves' vmem
        if (threadIdx.x == 0) {
            __hip_atomic_fetch_add(bar, 1u, __ATOMIC_RELAXED, __HIP_MEMORY_SCOPE_AGENT);
            unsigned tgt = (bar_base + (unsigned)s + 1u) * NBLK;
            int guard = 0;
            while (__hip_atomic_load(bar, __ATOMIC_RELAXED, __HIP_MEMORY_SCOPE_AGENT) < tgt
                   && guard < (1 << 18)) {
                __builtin_amdgcn_s_sleep(2);
                ++guard;
            }
        }
        __syncthreads();
    }
    // write back cell state
#pragma unroll
    for (int r = 0; r < 4; ++r)
        cb[(size_t)(m0 + quad * 4 + r) * HID + hid] = creg[r];
}

extern "C" void kernel_launch(void* const* d_in, const int* in_sizes, int n_in,
                              void* d_out, int out_size, void* d_ws, size_t ws_size,
                              hipStream_t stream) {
    const float* X  = (const float*)d_in[0];
    const float* h0 = (const float*)d_in[1];
    const float* c0 = (const float*)d_in[2];
    const float* W  = (const float*)d_in[3];
    const float* bb = (const float*)d_in[4];
    float* out = (float*)d_out;
    char* ws = (char*)d_ws;

    const size_t FIXED = 26218496ULL;
    int CH = 0;
    const int tiers[4] = {32, 16, 8, 4};
    for (int i = 0; i < 4; ++i)
        if (ws_size >= FIXED + (size_t)tiers[i] * 524288ULL) { CH = tiers[i]; break; }
    if (CH == 0) {
        zero_out<<<dim3(33024), 256, 0, stream>>>(out);
        return;
    }

    _Float16* WpH0 = (_Float16*)(ws + 0);
    _Float16* WpH1 = (_Float16*)(ws + 8388608);
    _Float16* WpX  = (_Float16*)(ws + 16777216);
    _Float16* ring = (_Float16*)(ws + 25165824);  // 4 slots x 65536 halfs
    float*    cb   = (float*)(ws + 25690112);
    unsigned* bar  = (unsigned*)(ws + 26214400);
    _Float16* Gc   = (_Float16*)(ws + 26218496);

    const size_t MSTRIDE = 2048 * 4096;  // per-layer W block (floats)
    const size_t FO = (size_t)SEQ * SL;  // 33,554,432
    const int MC = CH * BATCH;
    const int NCHUNK = SEQ / CH;

    zero_bar<<<dim3(1), 64, 0, stream>>>(bar);
    pack1<<<dim3(256, 8), 256, 0, stream>>>(W + 1024 * 4096, WpH0);
    pack1<<<dim3(256, 8), 256, 0, stream>>>(W + MSTRIDE + 1024 * 4096, WpH1);
    copy_f4<<<dim3(128), 256, 0, stream>>>(c0, cb);

    unsigned barBase = 0;
    for (int layer = 0; layer < 2; ++layer) {
        pack1<<<dim3(256, 8), 256, 0, stream>>>(W + (size_t)layer * MSTRIDE, WpX);
        const _Float16* Whp = layer ? WpH1 : WpH0;
        const float* bias = bb + (size_t)layer * 4096;
        float* cbl = cb + (size_t)layer * SL;
        _Float16* ringl = ring + (size_t)layer * 2 * SL;
        const float* Asrc = layer ? out : X;   // layer1 reads layer0 history from out
        for (int chunk = 0; chunk < NCHUNK; ++chunk) {
            gemm_in<<<dim3(MC / 128, 32), 256, 0, stream>>>(
                Asrc + (size_t)chunk * MC * 1024, WpX, bias, Gc);
            int t0 = chunk * CH;
            const float* h0i = (t0 == 0) ? (h0 + (size_t)layer * SL) : nullptr;
            float* lh = nullptr; float* lc = nullptr;
            if (chunk == NCHUNK - 1) {
                lh = out + FO + (size_t)layer * SL;
                lc = out + FO + 2 * SL + (size_t)layer * SL;
            }
            lstm_chunk<<<dim3(NBLK), 256, 0, stream>>>(
                Whp, Gc, cbl, ringl, h0i, out, lh, lc, bar, barBase, t0, CH);
            barBase += CH;
        }
    }
}